// Round 4
// baseline (250.132 us; speedup 1.0000x reference)
//
#include <hip/hip_runtime.h>
#include <stdint.h>

#define D_DIM 4096
#define N_ROWS 8192

typedef __attribute__((ext_vector_type(8))) short bfrag8;
typedef __attribute__((ext_vector_type(4))) float facc4;
typedef unsigned long long u64;

__device__ __forceinline__ uint32_t pack_bf16x2(float lo, float hi) {
    union { float f; uint32_t u; } a, b;
    a.f = lo; b.f = hi;
    return (b.u & 0xFFFF0000u) | (a.u >> 16);   // truncate-to-bf16
}

// ---------------------------------------------------------------------------
// Kernel 0: build fragment-ordered bf16 B-image from A (fp32 [128][4096]).
// Granule fb = chunk*16 + t*2 + ks; slot = fb*64 + lane (16 B):
//   A[16t + (lane&15)][chunk*64 + ks*32 + (lane>>4)*8 + j], j=0..7. (round 3,
// verified.) A is only 2 MB — gather reads here are negligible.
// ---------------------------------------------------------------------------
__global__ void __launch_bounds__(256)
prep_A(const float* __restrict__ A, uint32_t* __restrict__ Bimg) {
    const int S = blockIdx.x * 256 + threadIdx.x;  // 0..65535
    const int chunk = S >> 10;
    const int rest  = S & 1023;
    const int tks   = rest >> 6;
    const int lane  = rest & 63;
    const int t  = tks >> 1;
    const int ks = tks & 1;
    const int c  = lane & 15;
    const int q  = lane >> 4;
    const float* src = A + (size_t)(16 * t + c) * D_DIM + chunk * 64 + ks * 32 + q * 8;
    float4 f0 = *(const float4*)(src);
    float4 f1 = *(const float4*)(src + 4);
    uint4 o;
    o.x = pack_bf16x2(f0.x, f0.y);
    o.y = pack_bf16x2(f0.z, f0.w);
    o.z = pack_bf16x2(f1.x, f1.y);
    o.w = pack_bf16x2(f1.z, f1.w);
    *(uint4*)(Bimg + (size_t)S * 4) = o;
}

// ---------------------------------------------------------------------------
// Kernel 1: transpose-convert L (fp32 row-major) -> A-frag-ordered bf16 image.
// Block = (mw, kslab): 16 rows x 512 K. Global reads: lane-contiguous float4
// (1 KB/instr, fully consumed). LDS tile 16 x 528 bf16 (pad -> spread banks).
// Global writes: lane-contiguous uint4 (1 KB/instr).
// Image granule G = (mw*128 + chunk*2 + ks)*64 + lane holds
//   L[16mw + (lane&15)][chunk*64 + ks*32 + (lane>>4)*8 + j]  as bf16.
// ---------------------------------------------------------------------------
__global__ void __launch_bounds__(256)
prep_L(const float* __restrict__ L, uint32_t* __restrict__ Aimg) {
    __shared__ ushort T[16 * 528];
    const int tid = threadIdx.x, w = tid >> 6, lane = tid & 63;
    const int mw    = blockIdx.x >> 3;   // 0..511
    const int kslab = blockIdx.x & 7;    // 0..7 (512 floats each)
    const int k0 = kslab * 512;

    // stage 1: wave w loads rows 4w..4w+3; per row two fully-contiguous 1-KB reads
#pragma unroll
    for (int rr = 0; rr < 4; rr++) {
        const int r = 4 * w + rr;
        const float* src = L + (size_t)(mw * 16 + r) * D_DIM + k0;
#pragma unroll
        for (int h = 0; h < 2; h++) {
            float4 f = *(const float4*)(src + h * 256 + lane * 4);
            uint2 u = make_uint2(pack_bf16x2(f.x, f.y), pack_bf16x2(f.z, f.w));
            *(uint2*)&T[r * 528 + h * 256 + lane * 4] = u;
        }
    }
    __syncthreads();

    // stage 2: frag-gather from LDS, lane-contiguous global write
    const int c = lane & 15, q = lane >> 4;
#pragma unroll
    for (int p = 0; p < 4; p++) {
        const int cs  = 4 * w + p;          // 0..15
        const int chl = cs >> 1, ks = cs & 1;
        uint4 v = *(const uint4*)&T[c * 528 + chl * 64 + ks * 32 + q * 8];
        const size_t G = ((size_t)mw * 128 + (size_t)(kslab * 8 + chl) * 2 + ks) * 64 + lane;
        *(uint4*)(Aimg + G * 4) = v;
    }
}

// ---------------------------------------------------------------------------
// Kernel 2: GEMM, all loads lane-contiguous dwordx4 from bf16 frag images.
// Grid (4 outer-splits, 512 mw). Block = 4 waves = 4 inner K-splits of one
// 16-row tile; in-block LDS reduction -> one fp32 partial plane per outer.
// ---------------------------------------------------------------------------
__global__ void __launch_bounds__(256)
gemm_frag(const uint32_t* __restrict__ Aimg, const uint32_t* __restrict__ Bimg,
          float* __restrict__ partials) {
    __shared__ float red[3 * 2048];   // waves 1..3 park their tiles here (24 KB)
    const int tid = threadIdx.x, w = tid >> 6, lane = tid & 63;
    const int outer = blockIdx.x;     // 0..3
    const int mw    = blockIdx.y;     // 0..511
    const int split = outer * 4 + w;  // 0..15  -> chunks split*4 .. +4
    const int c = lane & 15, q = lane >> 4;

    facc4 acc[8];
#pragma unroll
    for (int t = 0; t < 8; t++) acc[t] = (facc4){0.f, 0.f, 0.f, 0.f};

#pragma unroll
    for (int ch = 0; ch < 4; ch++) {
        const int chunk = split * 4 + ch;
        const uint32_t* ab = Aimg + (((size_t)mw * 128 + chunk * 2) * 64 + lane) * 4;
        bfrag8 a0 = *(const bfrag8*)(ab);
        bfrag8 a1 = *(const bfrag8*)(ab + 256);
        const uint32_t* bb = Bimg + (size_t)chunk * 4096 + lane * 4;
#pragma unroll
        for (int t = 0; t < 8; t++) {
            bfrag8 b0 = *(const bfrag8*)(bb + (t * 2 + 0) * 256);
            acc[t] = __builtin_amdgcn_mfma_f32_16x16x32_bf16(a0, b0, acc[t], 0, 0, 0);
            bfrag8 b1 = *(const bfrag8*)(bb + (t * 2 + 1) * 256);
            acc[t] = __builtin_amdgcn_mfma_f32_16x16x32_bf16(a1, b1, acc[t], 0, 0, 0);
        }
    }

    // in-block reduce over the 4 inner splits.
    // C/D layout (m89/m91-verified): elem e = (4q + r)*128 + 16t + c
    if (w) {
        float* dst = red + (w - 1) * 2048;
#pragma unroll
        for (int t = 0; t < 8; t++)
#pragma unroll
            for (int r = 0; r < 4; r++)
                dst[(4 * q + r) * 128 + 16 * t + c] = acc[t][r];
    }
    __syncthreads();
    if (w == 0) {
        float* P = partials + (size_t)outer * (N_ROWS * 128) + (size_t)(mw * 16) * 128;
#pragma unroll
        for (int t = 0; t < 8; t++)
#pragma unroll
            for (int r = 0; r < 4; r++) {
                const int e = (4 * q + r) * 128 + 16 * t + c;
                P[e] = acc[t][r] + red[e] + red[2048 + e] + red[4096 + e];
            }
    }
}

// ---------------------------------------------------------------------------
// Kernel 3: reduce S partial planes, sign -> 128-bit key -> 64-bit fold.
// ---------------------------------------------------------------------------
__global__ void __launch_bounds__(256)
reduce_pack(const float* __restrict__ partials, u64* __restrict__ folded, int S) {
    const int row  = blockIdx.x * 4 + (threadIdx.x >> 6);
    const int lane = threadIdx.x & 63;
    float s0 = 0.f, s1 = 0.f;
    for (int s = 0; s < S; s++) {
        const float* P = partials + ((size_t)s * N_ROWS * 128) + (size_t)row * 128;
        s0 += P[lane];
        s1 += P[lane + 64];
    }
    u64 b0 = __ballot(s0 > 0.0f);
    u64 b1 = __ballot(s1 > 0.0f);
    if (lane == 0) folded[row] = b0 ^ b1;
}

// ---------------------------------------------------------------------------
// Kernel 4: ordered duplicate count, LDS-staged keys (round 3, verified).
// ---------------------------------------------------------------------------
__global__ void __launch_bounds__(256)
count_rows(const u64* __restrict__ folded, float* __restrict__ out) {
    __shared__ u64 K[N_ROWS];
    const int tid = threadIdx.x;
    for (int i = tid; i < N_ROWS / 2; i += 256)
        ((uint4*)K)[i] = ((const uint4*)folded)[i];
    __syncthreads();

    const int g    = blockIdx.x * 4 + (tid >> 6);
    const int lane = tid & 63;
    int rows[4];
    u64 my[4];
    int cnt[4] = {0, 0, 0, 0};
#pragma unroll
    for (int r = 0; r < 4; r++) {
        rows[r] = g + 2048 * r;
        my[r] = K[rows[r]];
    }
    const int maxrow = rows[3];
    for (int j = lane; j <= maxrow; j += 64) {
        u64 k = K[j];
#pragma unroll
        for (int r = 0; r < 4; r++)
            cnt[r] += (int)((j <= rows[r]) & (k == my[r]));
    }
#pragma unroll
    for (int r = 0; r < 4; r++) {
        int v = cnt[r];
#pragma unroll
        for (int o = 32; o; o >>= 1) v += __shfl_xor(v, o, 64);
        if (lane == 0) out[rows[r]] = rsqrtf((float)v);
    }
}

// ---------------------------------------------------------------------------
// Fallback GEMM (round 3, verified) if ws is unexpectedly small.
// ---------------------------------------------------------------------------
__global__ void __launch_bounds__(256, 3)
gemm_direct(const float* __restrict__ L, const uint32_t* __restrict__ Bimg,
            float* __restrict__ partials, int kpb) {
    const int tid  = threadIdx.x;
    const int lane = tid & 63;
    const int gw   = blockIdx.x * 4 + (tid >> 6);
    const int split = gw >> 9;
    const int mwave = gw & 511;
    const int c = lane & 15;
    const int q = lane >> 4;
    const float* lrow = L + (size_t)(16 * mwave + c) * D_DIM;

    facc4 acc[8];
#pragma unroll
    for (int t = 0; t < 8; t++) acc[t] = (facc4){0.f, 0.f, 0.f, 0.f};

    const int k0 = split * kpb;
#pragma unroll 2
    for (int k = k0; k < k0 + kpb; k++) {
        const int kc = k * 64;
        bfrag8 a[2];
#pragma unroll
        for (int ks = 0; ks < 2; ks++) {
            const float* p = lrow + kc + ks * 32 + q * 8;
            float4 f0 = *(const float4*)(p);
            float4 f1 = *(const float4*)(p + 4);
            uint4 u;
            u.x = pack_bf16x2(f0.x, f0.y);
            u.y = pack_bf16x2(f0.z, f0.w);
            u.z = pack_bf16x2(f1.x, f1.y);
            u.w = pack_bf16x2(f1.z, f1.w);
            a[ks] = *(bfrag8*)&u;
        }
        const uint32_t* bbase = Bimg + ((size_t)k * 16) * 256 + lane * 4;
#pragma unroll
        for (int t = 0; t < 8; t++) {
#pragma unroll
            for (int ks = 0; ks < 2; ks++) {
                bfrag8 b = *(const bfrag8*)(bbase + (t * 2 + ks) * 256);
                acc[t] = __builtin_amdgcn_mfma_f32_16x16x32_bf16(a[ks], b, acc[t], 0, 0, 0);
            }
        }
    }
    float* P = partials + (size_t)split * N_ROWS * 128 + (size_t)(16 * mwave) * 128;
#pragma unroll
    for (int t = 0; t < 8; t++)
#pragma unroll
        for (int r = 0; r < 4; r++)
            P[(4 * q + r) * 128 + 16 * t + c] = acc[t][r];
}

extern "C" void kernel_launch(void* const* d_in, const int* in_sizes, int n_in,
                              void* d_out, int out_size, void* d_ws, size_t ws_size,
                              hipStream_t stream) {
    const float* latent = (const float*)d_in[0];   // [128,64,4096] fp32
    const float* A      = (const float*)d_in[1];   // [128,4096] fp32
    float* out          = (float*)d_out;           // [8192] fp32

    // ws layout: Bimg 1 MB | folded 64 KB | Aimg 64 MB | partials 16 MB
    const size_t OFF_FOLDED = (size_t)1 << 20;
    const size_t OFF_AIMG   = OFF_FOLDED + ((size_t)1 << 16);
    const size_t OFF_PART   = OFF_AIMG + ((size_t)64 << 20);
    const size_t NEED       = OFF_PART + ((size_t)16 << 20);

    uint32_t* Bimg = (uint32_t*)d_ws;
    u64* folded    = (u64*)((char*)d_ws + OFF_FOLDED);

    prep_A<<<256, 256, 0, stream>>>(A, Bimg);

    if (ws_size >= NEED) {
        uint32_t* Aimg  = (uint32_t*)((char*)d_ws + OFF_AIMG);
        float* partials = (float*)((char*)d_ws + OFF_PART);
        prep_L<<<4096, 256, 0, stream>>>(latent, Aimg);
        gemm_frag<<<dim3(4, 512), 256, 0, stream>>>(Aimg, Bimg, partials);
        reduce_pack<<<2048, 256, 0, stream>>>(partials, folded, 4);
    } else {
        // fallback: round-3 path, partials right after folded
        float* partials = (float*)((char*)d_ws + OFF_AIMG);
        const size_t per_split = (size_t)N_ROWS * 128 * sizeof(float);
        int S = 1;
        if (ws_size >= OFF_AIMG + 8 * per_split)      S = 8;
        else if (ws_size >= OFF_AIMG + 4 * per_split) S = 4;
        else if (ws_size >= OFF_AIMG + 2 * per_split) S = 2;
        gemm_direct<<<128 * S, 256, 0, stream>>>(latent, Bimg, partials, 64 / S);
        reduce_pack<<<2048, 256, 0, stream>>>(partials, folded, S);
    }
    count_rows<<<512, 256, 0, stream>>>(folded, out);
}

// Round 5
// 230.465 us; speedup vs baseline: 1.0853x; 1.0853x over previous
//
#include <hip/hip_runtime.h>
#include <stdint.h>

#define D_DIM 4096
#define N_ROWS 8192

typedef __attribute__((ext_vector_type(8))) short bfrag8;
typedef __attribute__((ext_vector_type(16))) float facc16;
typedef unsigned long long u64;

__device__ __forceinline__ uint32_t pack_bf16x2(float lo, float hi) {
    union { float f; uint32_t u; } a, b;
    a.f = lo; b.f = hi;
    return (b.u & 0xFFFF0000u) | (a.u >> 16);   // truncate-to-bf16
}

// ---------------------------------------------------------------------------
// Kernel 0: build 32x32x16-frag-ordered bf16 B-image from A (fp32 [128][4096]).
// Granule g = (chunk*4 + ks)*4 + t  (chunk = 64-K slab, ks = 16-K MFMA step,
// t = 32-col n-tile). Slot = g*64 + lane (16 B):
//   A[32t + (lane&31)][chunk*64 + ks*16 + (lane>>5)*8 + j], j=0..7  (bf16)
// GEMM B-frag load = one lane-contiguous global_load_dwordx4 (1 KB/instr).
// A is 2 MB; gather reads here are negligible.
// ---------------------------------------------------------------------------
__global__ void __launch_bounds__(256)
prep_A(const float* __restrict__ A, uint32_t* __restrict__ Bimg) {
    const int S = blockIdx.x * 256 + threadIdx.x;  // 0..65535
    const int lane = S & 63;
    const int g = S >> 6;                          // 0..1023
    const int t = g & 3, ks = (g >> 2) & 3, chunk = g >> 4;
    const int n  = 32 * t + (lane & 31);
    const int k0 = chunk * 64 + ks * 16 + (lane >> 5) * 8;
    const float* src = A + (size_t)n * D_DIM + k0;
    float4 f0 = *(const float4*)(src);
    float4 f1 = *(const float4*)(src + 4);
    uint4 o;
    o.x = pack_bf16x2(f0.x, f0.y);
    o.y = pack_bf16x2(f0.z, f0.w);
    o.z = pack_bf16x2(f1.x, f1.y);
    o.w = pack_bf16x2(f1.z, f1.w);
    *(uint4*)(Bimg + (size_t)S * 4) = o;
}

// ---------------------------------------------------------------------------
// Kernel 1: 32x32x16 MFMA GEMM. Grid (4 outer, 256 mt); block = 4 waves =
// 4 inner K-splits of one 32-row tile. Wave: 32 rows x 128 cols x 4 chunks,
// 64 MFMAs, barrier-free K-loop. In-block LDS reduce -> fp32 partial plane.
// B-frag L2 traffic: 16 KB/chunk/wave -> 256 MB total (half of round 3/4).
// ---------------------------------------------------------------------------
__global__ void __launch_bounds__(256)
gemm32(const float* __restrict__ L, const uint32_t* __restrict__ Bimg,
       float* __restrict__ partials) {
    __shared__ float red[3 * 4096];    // waves 1..3 park 32x128 tiles (48 KB)
    const int tid = threadIdx.x, w = tid >> 6, lane = tid & 63;
    const int outer = blockIdx.x;      // 0..3
    const int mt    = blockIdx.y;      // 0..255
    const int split = outer * 4 + w;   // 0..15 -> chunks split*4 .. +4
    const int n31 = lane & 31, q8 = lane >> 5;
    const int row0 = mt * 32;

    // A-operand for 32x32x16: lane holds A[m = lane&31][k = (lane>>5)*8 + j]
    const float* lrow = L + (size_t)(row0 + n31) * D_DIM + q8 * 8;

    facc16 acc[4];
#pragma unroll
    for (int t = 0; t < 4; t++)
#pragma unroll
        for (int r = 0; r < 16; r++) acc[t][r] = 0.0f;

#pragma unroll
    for (int ch = 0; ch < 4; ch++) {
        const int chunk = split * 4 + ch;
        const int kc = chunk * 64;
        bfrag8 a[4];
#pragma unroll
        for (int ks = 0; ks < 4; ks++) {
            const float* p = lrow + kc + ks * 16;
            float4 f0 = *(const float4*)(p);
            float4 f1 = *(const float4*)(p + 4);
            uint4 u;
            u.x = pack_bf16x2(f0.x, f0.y);
            u.y = pack_bf16x2(f0.z, f0.w);
            u.z = pack_bf16x2(f1.x, f1.y);
            u.w = pack_bf16x2(f1.z, f1.w);
            a[ks] = *(bfrag8*)&u;
        }
        const uint32_t* bb = Bimg + (size_t)chunk * 4096 + lane * 4;
#pragma unroll
        for (int ks = 0; ks < 4; ks++)
#pragma unroll
            for (int t = 0; t < 4; t++) {
                bfrag8 b = *(const bfrag8*)(bb + (ks * 4 + t) * 256);
                acc[t] = __builtin_amdgcn_mfma_f32_32x32x16_bf16(a[ks], b, acc[t], 0, 0, 0);
            }
    }

    // C/D layout 32x32 (m74/m101-verified):
    //   col = lane&31, row = (reg&3) + 8*(reg>>2) + 4*(lane>>5)
    if (w) {
        float* dst = red + (w - 1) * 4096;
#pragma unroll
        for (int t = 0; t < 4; t++)
#pragma unroll
            for (int r = 0; r < 16; r++) {
                const int row_l = (r & 3) + 8 * (r >> 2) + 4 * q8;
                dst[row_l * 128 + 32 * t + n31] = acc[t][r];
            }
    }
    __syncthreads();
    if (w == 0) {
        float* P = partials + (size_t)outer * (N_ROWS * 128) + (size_t)row0 * 128;
#pragma unroll
        for (int t = 0; t < 4; t++)
#pragma unroll
            for (int r = 0; r < 16; r++) {
                const int row_l = (r & 3) + 8 * (r >> 2) + 4 * q8;
                const int e = row_l * 128 + 32 * t + n31;
                P[e] = acc[t][r] + red[e] + red[4096 + e] + red[8192 + e];
            }
    }
}

// ---------------------------------------------------------------------------
// Kernel 2: reduce 4 partial planes, sign -> 128-bit key -> 64-bit fold.
// One wave per row; lane covers cols (lane, lane+64).
// ---------------------------------------------------------------------------
__global__ void __launch_bounds__(256)
reduce_pack(const float* __restrict__ partials, u64* __restrict__ folded, int S) {
    const int row  = blockIdx.x * 4 + (threadIdx.x >> 6);
    const int lane = threadIdx.x & 63;
    float s0 = 0.f, s1 = 0.f;
    for (int s = 0; s < S; s++) {
        const float* P = partials + ((size_t)s * N_ROWS * 128) + (size_t)row * 128;
        s0 += P[lane];
        s1 += P[lane + 64];
    }
    u64 b0 = __ballot(s0 > 0.0f);
    u64 b1 = __ballot(s1 > 0.0f);
    if (lane == 0) folded[row] = b0 ^ b1;
}

// ---------------------------------------------------------------------------
// Kernel 3: ordered duplicate count, LDS-staged keys (verified since round 2).
// ---------------------------------------------------------------------------
__global__ void __launch_bounds__(256)
count_rows(const u64* __restrict__ folded, float* __restrict__ out) {
    __shared__ u64 K[N_ROWS];
    const int tid = threadIdx.x;
    for (int i = tid; i < N_ROWS / 2; i += 256)
        ((uint4*)K)[i] = ((const uint4*)folded)[i];
    __syncthreads();

    const int g    = blockIdx.x * 4 + (tid >> 6);
    const int lane = tid & 63;
    int rows[4];
    u64 my[4];
    int cnt[4] = {0, 0, 0, 0};
#pragma unroll
    for (int r = 0; r < 4; r++) {
        rows[r] = g + 2048 * r;
        my[r] = K[rows[r]];
    }
    const int maxrow = rows[3];
    for (int j = lane; j <= maxrow; j += 64) {
        u64 k = K[j];
#pragma unroll
        for (int r = 0; r < 4; r++)
            cnt[r] += (int)((j <= rows[r]) & (k == my[r]));
    }
#pragma unroll
    for (int r = 0; r < 4; r++) {
        int v = cnt[r];
#pragma unroll
        for (int o = 32; o; o >>= 1) v += __shfl_xor(v, o, 64);
        if (lane == 0) out[rows[r]] = rsqrtf((float)v);
    }
}

extern "C" void kernel_launch(void* const* d_in, const int* in_sizes, int n_in,
                              void* d_out, int out_size, void* d_ws, size_t ws_size,
                              hipStream_t stream) {
    const float* latent = (const float*)d_in[0];   // [128,64,4096] fp32
    const float* A      = (const float*)d_in[1];   // [128,4096] fp32
    float* out          = (float*)d_out;           // [8192] fp32

    // ws layout: Bimg 1 MB | folded 64 KB | partials 16 MB  (~17.1 MB total;
    // observed ws_size is 512 MB — fill counters — so this always fits)
    uint32_t* Bimg  = (uint32_t*)d_ws;
    u64* folded     = (u64*)((char*)d_ws + (1 << 20));
    float* partials = (float*)((char*)d_ws + (1 << 20) + (1 << 16));

    prep_A<<<256, 256, 0, stream>>>(A, Bimg);
    gemm32<<<dim3(4, 256), 256, 0, stream>>>(latent, Bimg, partials);
    reduce_pack<<<2048, 256, 0, stream>>>(partials, folded, 4);
    count_rows<<<512, 256, 0, stream>>>(folded, out);
}